// Round 5
// baseline (228.899 us; speedup 1.0000x reference)
//
#include <hip/hip_runtime.h>

#define N_NODES 50000
#define N_EDGES 800000
#define IN_SIZE 128
#define HIDDEN 128
#define OUT_SIZE 64

#define CHUNKS 128
#define CHUNK_EDGES 6250      // 128 * 6250 = 800000 exactly
#define GEMMA_TILES 1563      // ceil(50000/32)
#define GEMMA_SUPER 391       // ceil(1563/4) 4-tile super-blocks
#define FUSED_GRID (CHUNKS + GEMMA_SUPER)
#define NBS 196               // ceil(50000/256) block sums, granularity 256 nodes

static __device__ inline unsigned pack_bf16x2(float a, float b) {
    unsigned ua = __float_as_uint(a);
    unsigned ub = __float_as_uint(b);
    unsigned ra = (ua + 0x7fffu + ((ua >> 16) & 1u)) >> 16;        // RNE
    unsigned rb = (ub + 0x7fffu + ((ub >> 16) & 1u)) & 0xffff0000u;
    return ra | rb;
}

static __device__ inline unsigned pack_f16x2(float a, float b) {
    _Float16 ha = (_Float16)a, hb = (_Float16)b;       // RNE converts
    unsigned short ua = __builtin_bit_cast(unsigned short, ha);
    unsigned short ub = __builtin_bit_cast(unsigned short, hb);
    return (unsigned)ua | ((unsigned)ub << 16);
}

static __device__ inline float2 unpack_f16x2(unsigned u) {
    _Float16 lo = __builtin_bit_cast(_Float16, (unsigned short)(u & 0xffffu));
    _Float16 hi = __builtin_bit_cast(_Float16, (unsigned short)(u >> 16));
    return make_float2((float)lo, (float)hi);
}

static __device__ inline float bf_lo(unsigned w) { return __uint_as_float(w << 16); }
static __device__ inline float bf_hi(unsigned w) { return __uint_as_float(w & 0xffff0000u); }

// ---- fused launch: blocks [0,128) = LDS histogram role; rest = gemmA role ----
// hist: per-chunk dst/src counts + within-chunk rank (LDS atomics, no global atomics)
// gemmA: 4 independent 256-thread sub-tiles per 1024-thread block, t1 = bf16(h @ W1)
__global__ __launch_bounds__(1024) void fused_hist_gemmA(const int* __restrict__ src,
                                                         const int* __restrict__ dst,
                                                         unsigned char* __restrict__ cntD,
                                                         unsigned char* __restrict__ cntS,
                                                         unsigned char* __restrict__ rp,
                                                         const float* __restrict__ h,
                                                         const float* __restrict__ W1,
                                                         unsigned short* __restrict__ t1) {
    __shared__ __align__(16) unsigned char smem[131072];   // 128 KB (<=160 KB/CU)
    const int b = blockIdx.x;

    if (b < CHUNKS) {
        // ---- histogram role ----
        unsigned* hD = (unsigned*)smem;          // 12500 words = 50000 8-bit counters
        unsigned* hS = hD + 12500;
        const int t = threadIdx.x;
        for (int i = t; i < 12500; i += 1024) { hD[i] = 0u; hS[i] = 0u; }
        __syncthreads();
        const int base = b * CHUNK_EDGES;
        for (int i = t; i < CHUNK_EDGES; i += 1024) {
            int e = base + i;
            int d = dst[e];
            int s = src[e];
            unsigned shd = (unsigned)(d & 3) * 8u;
            unsigned old = atomicAdd(&hD[d >> 2], 1u << shd);
            rp[e] = (unsigned char)((old >> shd) & 0xffu);   // rank within chunk
            atomicAdd(&hS[s >> 2], 1u << ((unsigned)(s & 3) * 8u));
        }
        __syncthreads();
        unsigned* gD = (unsigned*)cntD + (size_t)b * 12500;
        unsigned* gS = (unsigned*)cntS + (size_t)b * 12500;
        for (int i = t; i < 12500; i += 1024) { gD[i] = hD[i]; gS[i] = hS[i]; }
        return;
    }

    // ---- gemmA role: sub-block = threadIdx.x>>8 handles one 32-row tile ----
    const int sub = threadIdx.x >> 8;
    const int t   = threadIdx.x & 255;
    int tile = (b - CHUNKS) * 4 + sub;
    if (tile >= GEMMA_TILES) tile = GEMMA_TILES - 1;   // benign duplicate of last tile

    float* sA = (float*)(smem + (size_t)sub * 32768);  // [32][128]
    float* sW = sA + 32 * 128;                         // [32][128]

    const int tx = t & 31;
    const int ty = t >> 5;
    const int n0 = tile * 32;

    for (int i = t; i < 1024; i += 256) {
        int n = i >> 5, c = i & 31;
        int gn = n0 + n;
        float4 v = make_float4(0.f, 0.f, 0.f, 0.f);
        if (gn < N_NODES) v = ((const float4*)(h + (size_t)gn * 128))[c];
        ((float4*)(sA + n * 128))[c] = v;
    }

    float4 acc[4];
    #pragma unroll
    for (int i = 0; i < 4; ++i) acc[i] = make_float4(0.f, 0.f, 0.f, 0.f);

    for (int kc = 0; kc < 4; ++kc) {
        __syncthreads();   // uniform across all 4 subs (same trip counts)
        for (int i = t; i < 1024; i += 256) {
            int k = i >> 5, c = i & 31;
            ((float4*)(sW + k * 128))[c] = ((const float4*)(W1 + (size_t)(kc * 32 + k) * 128))[c];
        }
        __syncthreads();
        #pragma unroll 8
        for (int k = 0; k < 32; ++k) {
            float4 w = ((float4*)(sW + k * 128))[tx];
            #pragma unroll
            for (int ni = 0; ni < 4; ++ni) {
                float a = sA[(ty * 4 + ni) * 128 + kc * 32 + k];
                acc[ni].x = fmaf(a, w.x, acc[ni].x);
                acc[ni].y = fmaf(a, w.y, acc[ni].y);
                acc[ni].z = fmaf(a, w.z, acc[ni].z);
                acc[ni].w = fmaf(a, w.w, acc[ni].w);
            }
        }
    }

    #pragma unroll
    for (int ni = 0; ni < 4; ++ni) {
        int gn = n0 + ty * 4 + ni;
        if (gn < N_NODES) {
            uint2 p;
            p.x = pack_bf16x2(acc[ni].x, acc[ni].y);
            p.y = pack_bf16x2(acc[ni].z, acc[ni].w);
            ((uint2*)(t1 + (size_t)gn * 128))[tx] = p;
        }
    }
}

// ---- fused: per-node chunk prefix (in-place) + norms + block-level scan ----
__global__ __launch_bounds__(256) void deg_scan_kernel(unsigned char* __restrict__ cntD,
                                                       const unsigned char* __restrict__ cntS,
                                                       int* __restrict__ row_ptr,
                                                       int* __restrict__ bsum,
                                                       float* __restrict__ norm_out,
                                                       float* __restrict__ norm_in) {
    const int t = threadIdx.x, lane = t & 63, w = t >> 6;
    const int n = blockIdx.x * 256 + t;
    unsigned sumD = 0u, sumS = 0u;
    if (n < N_NODES) {
        #pragma unroll 4
        for (int c = 0; c < CHUNKS; ++c) {
            size_t idx = (size_t)c * 50000 + n;
            unsigned v = cntD[idx];
            cntD[idx] = (unsigned char)sumD;   // exclusive prefix (total deg < 256)
            sumD += v;
            sumS += cntS[idx];
        }
        norm_in[n]  = rsqrtf((float)(sumD ? sumD : 1u));
        norm_out[n] = rsqrtf((float)(sumS ? sumS : 1u));
    }
    __shared__ int wsum[4];
    int v = (n < N_NODES) ? (int)sumD : 0;
    int incl = v;
    #pragma unroll
    for (int d = 1; d < 64; d <<= 1) {
        int u = __shfl_up(incl, d, 64);
        if (lane >= d) incl += u;
    }
    if (lane == 63) wsum[w] = incl;
    __syncthreads();
    int woff = 0, total = 0;
    #pragma unroll
    for (int j = 0; j < 4; ++j) {
        int s = wsum[j];
        if (j < w) woff += s;
        total += s;
    }
    if (n < N_NODES) row_ptr[n] = woff + incl - v;
    if (t == 0) bsum[blockIdx.x] = total;
}

// ---- scan of 196 block sums (single wave, chunks with carry) ----
__global__ __launch_bounds__(64) void scan2_kernel(int* __restrict__ bsum,
                                                   int* __restrict__ row_ptr) {
    const int lane = threadIdx.x;
    int carry = 0;
    for (int base = 0; base < NBS; base += 64) {
        int t = base + lane;
        int v = (t < NBS) ? bsum[t] : 0;
        int incl = v;
        #pragma unroll
        for (int d = 1; d < 64; d <<= 1) {
            int u = __shfl_up(incl, d, 64);
            if (lane >= d) incl += u;
        }
        int excl = carry + incl - v;
        if (t < NBS) bsum[t] = excl;
        if (t == NBS - 1) row_ptr[N_NODES] = N_EDGES - excl;
        carry += __shfl(incl, 63, 64);
    }
}

// ---- atomic-free CSR placement: row_ptr + bsum + chunk prefix + rank ----
__global__ __launch_bounds__(256) void place_kernel(const int* __restrict__ src,
                                                    const int* __restrict__ dst,
                                                    const int* __restrict__ row_ptr,
                                                    const int* __restrict__ bsum,
                                                    const unsigned char* __restrict__ cntD,
                                                    const unsigned char* __restrict__ rp,
                                                    int* __restrict__ eidx) {
    int e = blockIdx.x * 256 + threadIdx.x;
    if (e < N_EDGES) {
        int d = dst[e];
        int c = e / CHUNK_EDGES;
        int pos = row_ptr[d] + bsum[d >> 8] + (int)cntD[(size_t)c * 50000 + d] + (int)rp[e];
        eidx[pos] = src[e];
    }
}

// ---------------- GEMM-B: t2 = fp16(h1p @ W2)  (N x 128 @ 128 x 64) ----------------
__global__ __launch_bounds__(256) void gemmB_kernel(const float* __restrict__ h1p,
                                                    const float* __restrict__ W2,
                                                    unsigned short* __restrict__ t2h) {
    __shared__ float sA[32][128];
    __shared__ float sW[128][64];
    const int t  = threadIdx.x;
    const int tx = t & 15;
    const int ty = t >> 4;
    const int n0 = blockIdx.x * 32;

    for (int i = t; i < 1024; i += 256) {
        int n = i >> 5, c = i & 31;
        int gn = n0 + n;
        float4 v = make_float4(0.f, 0.f, 0.f, 0.f);
        if (gn < N_NODES) v = ((const float4*)(h1p + (size_t)gn * 128))[c];
        ((float4*)sA[n])[c] = v;
    }
    for (int i = t; i < 2048; i += 256) {
        int k = i >> 4, c = i & 15;
        ((float4*)sW[k])[c] = ((const float4*)(W2 + (size_t)k * 64))[c];
    }
    __syncthreads();

    float4 a0 = make_float4(0.f, 0.f, 0.f, 0.f);
    float4 a1 = make_float4(0.f, 0.f, 0.f, 0.f);
    #pragma unroll 8
    for (int k = 0; k < 128; ++k) {
        float4 w = ((float4*)sW[k])[tx];
        float x0 = sA[ty * 2 + 0][k];
        float x1 = sA[ty * 2 + 1][k];
        a0.x = fmaf(x0, w.x, a0.x); a0.y = fmaf(x0, w.y, a0.y);
        a0.z = fmaf(x0, w.z, a0.z); a0.w = fmaf(x0, w.w, a0.w);
        a1.x = fmaf(x1, w.x, a1.x); a1.y = fmaf(x1, w.y, a1.y);
        a1.z = fmaf(x1, w.z, a1.z); a1.w = fmaf(x1, w.w, a1.w);
    }

    #pragma unroll
    for (int ni = 0; ni < 2; ++ni) {
        int gn = n0 + ty * 2 + ni;
        if (gn < N_NODES) {
            float4 a = ni ? a1 : a0;
            uint2 p;
            p.x = pack_f16x2(a.x, a.y);
            p.y = pack_f16x2(a.z, a.w);
            ((uint2*)(t2h + (size_t)gn * 64))[tx] = p;
        }
    }
}

// ---------------- pull aggregation, 128 bf16 feats: 2 edges per wave-round ----------------
// lanes 0-31 = edge a, lanes 32-63 = edge b; each lane loads uint2 (4 bf16 feats).
// One VMEM inst covers 2 edges (512B). h1p[n] = relu(ni*sum norm_out[s]*t1[s] + b1)*no
__global__ __launch_bounds__(256) void pull128_kernel(const unsigned short* __restrict__ xb,
                                                      const int* __restrict__ row_ptr,
                                                      const int* __restrict__ bsum,
                                                      const int* __restrict__ eidx,
                                                      const float* __restrict__ b1,
                                                      const float* __restrict__ norm_in,
                                                      const float* __restrict__ norm_out,
                                                      float* __restrict__ out) {
    int node = blockIdx.x * 4 + (threadIdx.x >> 6);
    node = __builtin_amdgcn_readfirstlane(node);
    const int lane = threadIdx.x & 63;
    const int half = lane >> 5;
    const int fl = lane & 31;
    const int beg = __builtin_amdgcn_readfirstlane(row_ptr[node] + bsum[node >> 8]);
    const int end = __builtin_amdgcn_readfirstlane(row_ptr[node + 1] + bsum[(node + 1) >> 8]);

    float4 acc0 = make_float4(0.f, 0.f, 0.f, 0.f);
    float4 acc1 = make_float4(0.f, 0.f, 0.f, 0.f);
    float4 acc2 = make_float4(0.f, 0.f, 0.f, 0.f);
    float4 acc3 = make_float4(0.f, 0.f, 0.f, 0.f);

    for (int base = beg; base < end; base += 64) {
        const int cnt = min(64, end - base);
        int my_e = 0;
        float my_n = 0.f;
        if (lane < cnt) {
            my_e = eidx[base + lane];
            my_n = norm_out[my_e];
        }
        int k = 0;
        for (; k + 7 < cnt; k += 8) {      // 4 pairs = 8 edges, 4 loads in flight
            int sl0 = __builtin_amdgcn_readlane(my_e, k);
            int sh0 = __builtin_amdgcn_readlane(my_e, k + 1);
            int sl1 = __builtin_amdgcn_readlane(my_e, k + 2);
            int sh1 = __builtin_amdgcn_readlane(my_e, k + 3);
            int sl2 = __builtin_amdgcn_readlane(my_e, k + 4);
            int sh2 = __builtin_amdgcn_readlane(my_e, k + 5);
            int sl3 = __builtin_amdgcn_readlane(my_e, k + 6);
            int sh3 = __builtin_amdgcn_readlane(my_e, k + 7);
            float nl0 = __int_as_float(__builtin_amdgcn_readlane(__float_as_int(my_n), k));
            float nh0 = __int_as_float(__builtin_amdgcn_readlane(__float_as_int(my_n), k + 1));
            float nl1 = __int_as_float(__builtin_amdgcn_readlane(__float_as_int(my_n), k + 2));
            float nh1 = __int_as_float(__builtin_amdgcn_readlane(__float_as_int(my_n), k + 3));
            float nl2 = __int_as_float(__builtin_amdgcn_readlane(__float_as_int(my_n), k + 4));
            float nh2 = __int_as_float(__builtin_amdgcn_readlane(__float_as_int(my_n), k + 5));
            float nl3 = __int_as_float(__builtin_amdgcn_readlane(__float_as_int(my_n), k + 6));
            float nh3 = __int_as_float(__builtin_amdgcn_readlane(__float_as_int(my_n), k + 7));
            int s0 = half ? sh0 : sl0;  float n0 = half ? nh0 : nl0;
            int s1 = half ? sh1 : sl1;  float n1 = half ? nh1 : nl1;
            int s2 = half ? sh2 : sl2;  float n2 = half ? nh2 : nl2;
            int s3 = half ? sh3 : sl3;  float n3 = half ? nh3 : nl3;
            uint2 u0 = ((const uint2*)(xb + (size_t)s0 * 128))[fl];
            uint2 u1 = ((const uint2*)(xb + (size_t)s1 * 128))[fl];
            uint2 u2 = ((const uint2*)(xb + (size_t)s2 * 128))[fl];
            uint2 u3 = ((const uint2*)(xb + (size_t)s3 * 128))[fl];
            acc0.x = fmaf(bf_lo(u0.x), n0, acc0.x);
            acc0.y = fmaf(bf_hi(u0.x), n0, acc0.y);
            acc0.z = fmaf(bf_lo(u0.y), n0, acc0.z);
            acc0.w = fmaf(bf_hi(u0.y), n0, acc0.w);
            acc1.x = fmaf(bf_lo(u1.x), n1, acc1.x);
            acc1.y = fmaf(bf_hi(u1.x), n1, acc1.y);
            acc1.z = fmaf(bf_lo(u1.y), n1, acc1.z);
            acc1.w = fmaf(bf_hi(u1.y), n1, acc1.w);
            acc2.x = fmaf(bf_lo(u2.x), n2, acc2.x);
            acc2.y = fmaf(bf_hi(u2.x), n2, acc2.y);
            acc2.z = fmaf(bf_lo(u2.y), n2, acc2.z);
            acc2.w = fmaf(bf_hi(u2.y), n2, acc2.w);
            acc3.x = fmaf(bf_lo(u3.x), n3, acc3.x);
            acc3.y = fmaf(bf_hi(u3.x), n3, acc3.y);
            acc3.z = fmaf(bf_lo(u3.y), n3, acc3.z);
            acc3.w = fmaf(bf_hi(u3.y), n3, acc3.w);
        }
        for (; k + 1 < cnt; k += 2) {      // single pair
            int sl = __builtin_amdgcn_readlane(my_e, k);
            int sh = __builtin_amdgcn_readlane(my_e, k + 1);
            float nl = __int_as_float(__builtin_amdgcn_readlane(__float_as_int(my_n), k));
            float nh = __int_as_float(__builtin_amdgcn_readlane(__float_as_int(my_n), k + 1));
            int s = half ? sh : sl;  float n = half ? nh : nl;
            uint2 u = ((const uint2*)(xb + (size_t)s * 128))[fl];
            acc0.x = fmaf(bf_lo(u.x), n, acc0.x);
            acc0.y = fmaf(bf_hi(u.x), n, acc0.y);
            acc0.z = fmaf(bf_lo(u.y), n, acc0.z);
            acc0.w = fmaf(bf_hi(u.y), n, acc0.w);
        }
        if (k < cnt) {                     // odd tail: upper half replays with n=0
            int sl = __builtin_amdgcn_readlane(my_e, k);
            float nl = __int_as_float(__builtin_amdgcn_readlane(__float_as_int(my_n), k));
            float n = half ? 0.f : nl;
            uint2 u = ((const uint2*)(xb + (size_t)sl * 128))[fl];
            acc0.x = fmaf(bf_lo(u.x), n, acc0.x);
            acc0.y = fmaf(bf_hi(u.x), n, acc0.y);
            acc0.z = fmaf(bf_lo(u.y), n, acc0.z);
            acc0.w = fmaf(bf_hi(u.y), n, acc0.w);
        }
    }

    // combine unroll slots, then cross-half reduce (features 4fl..4fl+3)
    float4 s;
    s.x = (acc0.x + acc1.x) + (acc2.x + acc3.x);
    s.y = (acc0.y + acc1.y) + (acc2.y + acc3.y);
    s.z = (acc0.z + acc1.z) + (acc2.z + acc3.z);
    s.w = (acc0.w + acc1.w) + (acc2.w + acc3.w);
    s.x += __shfl_xor(s.x, 32, 64);
    s.y += __shfl_xor(s.y, 32, 64);
    s.z += __shfl_xor(s.z, 32, 64);
    s.w += __shfl_xor(s.w, 32, 64);

    if (half == 0) {
        float ni = norm_in[node];
        float no = norm_out[node];
        float4 bb = ((const float4*)b1)[fl];
        float4 r;
        r.x = fmaxf(fmaf(s.x, ni, bb.x), 0.f) * no;
        r.y = fmaxf(fmaf(s.y, ni, bb.y), 0.f) * no;
        r.z = fmaxf(fmaf(s.z, ni, bb.z), 0.f) * no;
        r.w = fmaxf(fmaf(s.w, ni, bb.w), 0.f) * no;
        ((float4*)(out + (size_t)node * 128))[fl] = r;
    }
}

// ---------------- pull aggregation, 64 fp16 feats, 2 edges per wave-round ----------------
__global__ __launch_bounds__(256) void pull64_kernel(const unsigned* __restrict__ x,
                                                     const int* __restrict__ row_ptr,
                                                     const int* __restrict__ bsum,
                                                     const int* __restrict__ eidx,
                                                     const float* __restrict__ b2,
                                                     const float* __restrict__ norm_in,
                                                     float* __restrict__ out) {
    int node = blockIdx.x * 4 + (threadIdx.x >> 6);
    node = __builtin_amdgcn_readfirstlane(node);
    const int lane = threadIdx.x & 63;
    const int half = lane >> 5;
    const int fl = lane & 31;
    const int beg = __builtin_amdgcn_readfirstlane(row_ptr[node] + bsum[node >> 8]);
    const int end = __builtin_amdgcn_readfirstlane(row_ptr[node + 1] + bsum[(node + 1) >> 8]);

    float2 a0 = make_float2(0.f, 0.f);
    float2 a1 = make_float2(0.f, 0.f);
    float2 a2 = make_float2(0.f, 0.f);
    float2 a3 = make_float2(0.f, 0.f);

    for (int base = beg; base < end; base += 64) {
        const int cnt = min(64, end - base);
        int my_e = (lane < cnt) ? eidx[base + lane] : 0;
        int k = 0;
        for (; k + 7 < cnt; k += 8) {
            int sa0 = __builtin_amdgcn_readlane(my_e, k);
            int sb0 = __builtin_amdgcn_readlane(my_e, k + 1);
            int sa1 = __builtin_amdgcn_readlane(my_e, k + 2);
            int sb1 = __builtin_amdgcn_readlane(my_e, k + 3);
            int sa2 = __builtin_amdgcn_readlane(my_e, k + 4);
            int sb2 = __builtin_amdgcn_readlane(my_e, k + 5);
            int sa3 = __builtin_amdgcn_readlane(my_e, k + 6);
            int sb3 = __builtin_amdgcn_readlane(my_e, k + 7);
            int e0 = half ? sb0 : sa0;
            int e1 = half ? sb1 : sa1;
            int e2 = half ? sb2 : sa2;
            int e3 = half ? sb3 : sa3;
            unsigned u0 = x[(size_t)e0 * 32 + fl];
            unsigned u1 = x[(size_t)e1 * 32 + fl];
            unsigned u2 = x[(size_t)e2 * 32 + fl];
            unsigned u3 = x[(size_t)e3 * 32 + fl];
            float2 v0 = unpack_f16x2(u0);
            float2 v1 = unpack_f16x2(u1);
            float2 v2 = unpack_f16x2(u2);
            float2 v3 = unpack_f16x2(u3);
            a0.x += v0.x; a0.y += v0.y;
            a1.x += v1.x; a1.y += v1.y;
            a2.x += v2.x; a2.y += v2.y;
            a3.x += v3.x; a3.y += v3.y;
        }
        for (; k + 1 < cnt; k += 2) {
            int sa = __builtin_amdgcn_readlane(my_e, k);
            int sb = __builtin_amdgcn_readlane(my_e, k + 1);
            int e0 = half ? sb : sa;
            unsigned u = x[(size_t)e0 * 32 + fl];
            float2 v = unpack_f16x2(u);
            a0.x += v.x; a0.y += v.y;
        }
        if (k < cnt) {
            int sa = __builtin_amdgcn_readlane(my_e, k);
            if (half == 0) {
                unsigned u = x[(size_t)sa * 32 + fl];
                float2 v = unpack_f16x2(u);
                a0.x += v.x; a0.y += v.y;
            }
        }
    }

    float ax = (a0.x + a1.x) + (a2.x + a3.x);
    float ay = (a0.y + a1.y) + (a2.y + a3.y);
    ax += __shfl_xor(ax, 32, 64);
    ay += __shfl_xor(ay, 32, 64);
    if (half == 0) {
        float ni = norm_in[node];
        float2 bb = ((const float2*)b2)[fl];
        float2 r;
        r.x = fmaxf(fmaf(ax, ni, bb.x), 0.f);
        r.y = fmaxf(fmaf(ay, ni, bb.y), 0.f);
        ((float2*)(out + (size_t)node * 64))[fl] = r;
    }
}

extern "C" void kernel_launch(void* const* d_in, const int* in_sizes, int n_in,
                              void* d_out, int out_size, void* d_ws, size_t ws_size,
                              hipStream_t stream) {
    const float* h  = (const float*)d_in[0];
    const float* W1 = (const float*)d_in[1];
    const float* b1 = (const float*)d_in[2];
    const float* W2 = (const float*)d_in[3];
    const float* b2 = (const float*)d_in[4];
    const int* src  = (const int*)d_in[5];
    const int* dst  = (const int*)d_in[6];
    float* out = (float*)d_out;

    char* ws = (char*)d_ws;
    size_t off = 0;
    auto alloc = [&](size_t bytes) {
        void* p = ws + off;
        off = (off + bytes + 255) & ~(size_t)255;
        return p;
    };
    float* norm_out   = (float*)alloc(N_NODES * sizeof(float));
    float* norm_in    = (float*)alloc(N_NODES * sizeof(float));
    int* row_ptr      = (int*)alloc((N_NODES + 1) * sizeof(int));
    int* bsum         = (int*)alloc(NBS * sizeof(int));
    int* eidx         = (int*)alloc((size_t)N_EDGES * sizeof(int));                       // 3.2 MB
    unsigned short* t1 = (unsigned short*)alloc((size_t)N_NODES * 128 * sizeof(short));   // 12.8 MB bf16 (reused as fp16 t2)
    float* h1p        = (float*)alloc((size_t)N_NODES * 128 * sizeof(float));             // 25.6 MB

    // hist/prefix scratch aliases into h1p (dead until pull128 writes h1p):
    unsigned char* cntD = (unsigned char*)h1p;                    // 128 * 50000 = 6.4 MB
    unsigned char* cntS = cntD + (size_t)CHUNKS * 50000;          // 6.4 MB
    unsigned char* rp   = cntS + (size_t)CHUNKS * 50000;          // 0.8 MB
    unsigned short* t2h = t1;    // t1 dead after pull128; 50000*64*2 = 6.4 MB fits

    // overlapped: histogram role (128 blocks) || gemmA role (391 blocks x 4 tiles)
    fused_hist_gemmA<<<FUSED_GRID, 1024, 0, stream>>>(src, dst, cntD, cntS, rp, h, W1, t1);

    // per-node chunk prefix + norms + block scan -> partial row_ptr + bsum
    deg_scan_kernel<<<NBS, 256, 0, stream>>>(cntD, cntS, row_ptr, bsum, norm_out, norm_in);

    // scan of block sums (also writes row_ptr[N_NODES])
    scan2_kernel<<<1, 64, 0, stream>>>(bsum, row_ptr);

    // atomic-free CSR placement
    place_kernel<<<(N_EDGES + 255) / 256, 256, 0, stream>>>(src, dst, row_ptr, bsum, cntD, rp, eidx);

    // layer 1 pull (bf16 gather, paired edges; per-edge norm as readlane+cndmask)
    pull128_kernel<<<N_NODES / 4, 256, 0, stream>>>(t1, row_ptr, bsum, eidx, b1,
                                                    norm_in, norm_out, h1p);

    // layer 2
    gemmB_kernel<<<(N_NODES + 31) / 32, 256, 0, stream>>>(h1p, W2, t2h);
    pull64_kernel<<<N_NODES / 4, 256, 0, stream>>>((const unsigned*)t2h, row_ptr, bsum, eidx,
                                                   b2, norm_in, out);
}